// Round 1
// baseline (619.212 us; speedup 1.0000x reference)
//
#include <hip/hip_runtime.h>

typedef __bf16 bf16_t;
typedef __bf16 bf16x8 __attribute__((ext_vector_type(8)));
typedef __bf16 bf16x2 __attribute__((ext_vector_type(2)));
typedef float f32x4 __attribute__((ext_vector_type(4)));

#define TOK   75264   // 24 * 56 * 56 tokens
#define NWIN  1536    // 24 * 8 * 8 windows
#define DD    384
#define DD3   1152
#define NHEAD 12
#define HD    32
#define NTOK  49      // tokens per window

// ---------------- K1: LayerNorm + window partition + bf16 cast ----------------
// one wave per token (window-ordered); writes xw[win*49+n][384] bf16
__global__ __launch_bounds__(64) void k_ln(const float* __restrict__ x,
                                           const float* __restrict__ g,
                                           const float* __restrict__ b,
                                           bf16_t* __restrict__ xw) {
  int row = blockIdx.x;                 // win*49 + n
  int win = row / NTOK, n = row - win * NTOK;
  int bt = win >> 6, wrem = win & 63;
  int n7 = n / 7;
  int hh = (wrem >> 3) * 7 + n7;
  int wc = (wrem & 7) * 7 + (n - n7 * 7);
  const float* xp = x + ((size_t)bt * 3136 + hh * 56 + wc) * DD;
  int lane = threadIdx.x;
  float2 v[3];
  float s = 0.f, s2 = 0.f;
  for (int i = 0; i < 3; i++) {
    float2 t = *(const float2*)(xp + 2 * lane + 128 * i);
    v[i] = t;
    s += t.x + t.y; s2 += t.x * t.x + t.y * t.y;
  }
  for (int off = 1; off < 64; off <<= 1) {
    s += __shfl_xor(s, off);
    s2 += __shfl_xor(s2, off);
  }
  float mu = s * (1.f / 384.f);
  float rs = rsqrtf(s2 * (1.f / 384.f) - mu * mu + 1e-5f);
  bf16_t* op = xw + (size_t)row * DD;
  for (int i = 0; i < 3; i++) {
    int d = 2 * lane + 128 * i;
    float2 gg = *(const float2*)(g + d);
    float2 bb = *(const float2*)(b + d);
    bf16x2 y;
    y[0] = (bf16_t)((v[i].x - mu) * rs * gg.x + bb.x);
    y[1] = (bf16_t)((v[i].y - mu) * rs * gg.y + bb.y);
    *(bf16x2*)(op + d) = y;
  }
}

// ---------------- K2: transpose + cast weights (R x C fp32 -> C x R bf16) ----------------
__global__ __launch_bounds__(256) void k_transpose(const float* __restrict__ src,
                                                   bf16_t* __restrict__ dst,
                                                   int R, int C) {
  __shared__ float t[32][33];
  int nbc = C / 32;
  int bc = blockIdx.x % nbc, br = blockIdx.x / nbc;
  int lx = threadIdx.x & 31, ly = threadIdx.x >> 5;   // 32 x 8
  for (int i = 0; i < 32; i += 8)
    t[ly + i][lx] = src[(size_t)(br * 32 + ly + i) * C + bc * 32 + lx];
  __syncthreads();
  for (int i = 0; i < 32; i += 8)
    dst[(size_t)(bc * 32 + ly + i) * R + br * 32 + lx] = (bf16_t)t[lx][ly + i];
}

// ---------------- K3/K5: 128x128 bf16 MFMA GEMM (m97 structure, B^T input) ----------------
// MODE 0: qkv epilogue -> q/k/v [win][head][49][32] bf16
// MODE 1: proj epilogue -> un-window to fp32 output
template <int MODE>
__global__ __launch_bounds__(256) void k_gemm(
    const bf16_t* __restrict__ A,    // [M][384] row-major
    const bf16_t* __restrict__ BT,   // [N][384] row-major (transposed weight)
    const float* __restrict__ bias,  // [N]
    bf16_t* __restrict__ oq, bf16_t* __restrict__ ok, bf16_t* __restrict__ ov,
    float* __restrict__ out) {
  __shared__ bf16_t As[128 * 32];
  __shared__ bf16_t Bs[128 * 32];
  const int tid = threadIdx.x, wave = tid >> 6, lane = tid & 63;
  const int tn = blockIdx.x, tm = blockIdx.y;   // tn fastest: weight tile L2-resident
  const int K = 384;

  // staging: each wave covers 32 rows of its tile (2 issues of 64 lanes x 16B)
  const bf16_t* ag = A + (size_t)(tm * 128 + wave * 32 + (lane >> 2)) * K + (lane & 3) * 8;
  const bf16_t* bg = BT + (size_t)(tn * 128 + wave * 32 + (lane >> 2)) * K + (lane & 3) * 8;
  char* asl = (char*)&As[0] + wave * 2048;
  char* bsl = (char*)&Bs[0] + wave * 2048;

  const int wm = (wave & 1) * 64, wn = (wave >> 1) * 64;
  const int l16 = lane & 15, quad = lane >> 4;
  f32x4 acc[4][4] = {};

  for (int kk = 0; kk < K; kk += 32) {
    __syncthreads();  // previous compute done before LDS overwrite
    __builtin_amdgcn_global_load_lds((const __attribute__((address_space(1))) void*)(ag),
                                     (__attribute__((address_space(3))) void*)(asl), 16, 0, 0);
    __builtin_amdgcn_global_load_lds((const __attribute__((address_space(1))) void*)(ag + 16 * K),
                                     (__attribute__((address_space(3))) void*)(asl + 1024), 16, 0, 0);
    __builtin_amdgcn_global_load_lds((const __attribute__((address_space(1))) void*)(bg),
                                     (__attribute__((address_space(3))) void*)(bsl), 16, 0, 0);
    __builtin_amdgcn_global_load_lds((const __attribute__((address_space(1))) void*)(bg + 16 * K),
                                     (__attribute__((address_space(3))) void*)(bsl + 1024), 16, 0, 0);
    ag += 32; bg += 32;
    __syncthreads();  // drains vmcnt before barrier -> staging complete
    bf16x8 af[4], bf[4];
    for (int t = 0; t < 4; t++) {
      af[t] = *(const bf16x8*)&As[(wm + t * 16 + l16) * 32 + quad * 8];
      bf[t] = *(const bf16x8*)&Bs[(wn + t * 16 + l16) * 32 + quad * 8];
    }
    for (int mt = 0; mt < 4; mt++)
      for (int nt = 0; nt < 4; nt++)
        acc[mt][nt] = __builtin_amdgcn_mfma_f32_16x16x32_bf16(af[mt], bf[nt], acc[mt][nt], 0, 0, 0);
  }

  // epilogue: C/D layout col = lane&15, row = quad*4 + reg  [m89-verified]
  const int col0 = tn * 128 + wn + l16;
  const int row0 = tm * 128 + wm + quad * 4;
  if constexpr (MODE == 0) {
    int qi = tn / 3;  // 3 column-tiles (384 cols) per q/k/v
    bf16_t* dst = (qi == 0) ? oq : ((qi == 1) ? ok : ov);
    for (int mt = 0; mt < 4; mt++) {
      for (int r = 0; r < 4; r++) {
        int row = row0 + mt * 16 + r;
        int win = row / NTOK, n = row - win * NTOK;
        for (int nt = 0; nt < 4; nt++) {
          int col = col0 + nt * 16;
          float val = acc[mt][nt][r] + bias[col];
          int cidx = col - qi * 384;
          int head = cidx >> 5, d = cidx & 31;
          dst[(((size_t)(win * NHEAD + head) * NTOK + n) << 5) + d] = (bf16_t)val;
        }
      }
    }
  } else {
    for (int mt = 0; mt < 4; mt++) {
      for (int r = 0; r < 4; r++) {
        int row = row0 + mt * 16 + r;
        int win = row / NTOK, n = row - win * NTOK;
        int bt = win >> 6, wrem = win & 63;
        int n7 = n / 7;
        int hh = (wrem >> 3) * 7 + n7;
        int wc = (wrem & 7) * 7 + (n - n7 * 7);
        float* op = out + ((size_t)bt * 3136 + hh * 56 + wc) * DD;
        for (int nt = 0; nt < 4; nt++) {
          int col = col0 + nt * 16;
          op[col] = acc[mt][nt][r] + bias[col];
        }
      }
    }
  }
}

// ---------------- K4: windowed attention, one wave per (win, head) ----------------
__global__ __launch_bounds__(64) void k_attn(const bf16_t* __restrict__ q,
                                             const bf16_t* __restrict__ k,
                                             const bf16_t* __restrict__ v,
                                             const float* __restrict__ table,
                                             bf16_t* __restrict__ O) {
  __shared__ bf16_t P[64 * 64];   // softmax probs, A-operand layout (row-major [64][64])
  __shared__ bf16_t Vs[64 * 32];  // V, zero-padded to 64 rows
  const int wh = blockIdx.x;      // win*12 + head
  const int head = wh % NHEAD, win = wh / NHEAD;
  const int lane = threadIdx.x, l16 = lane & 15, quad = lane >> 4;
  const bf16_t* qp = q + (size_t)wh * NTOK * HD;
  const bf16_t* kp = k + (size_t)wh * NTOK * HD;
  const bf16_t* vp = v + (size_t)wh * NTOK * HD;

  // stage V (49x32 -> 64x32, zero pad). chunks of 8 elems, coalesced.
  bf16x8 zz = {};
  for (int i = 0; i < 4; i++) {
    int c = lane + 64 * i;                // chunk id, 256 chunks total
    bf16x8 val = zz;
    if (c < NTOK * 4) val = *(const bf16x8*)(vp + c * 8);
    *(bf16x8*)(Vs + c * 8) = val;
  }

  // q/k fragments straight from global: A[m][kd], m=l16(+16*mt), kd=quad*8+j (16B contiguous)
  bf16x8 qf[4], kf[4];
  for (int t = 0; t < 4; t++) {
    int m = t * 16 + l16;
    if (m < NTOK) {
      qf[t] = *(const bf16x8*)(qp + m * HD + quad * 8);
      kf[t] = *(const bf16x8*)(kp + m * HD + quad * 8);
    } else { qf[t] = zz; kf[t] = zz; }
  }

  // S = q k^T  (64x64 padded, hd=32 = one K step)
  f32x4 S[4][4] = {};
  for (int mt = 0; mt < 4; mt++)
    for (int nt = 0; nt < 4; nt++)
      S[mt][nt] = __builtin_amdgcn_mfma_f32_16x16x32_bf16(qf[mt], kf[nt], S[mt][nt], 0, 0, 0);

  // scale + rel-bias + masked softmax per row; row lives in one quad (16 lanes)
  const float scale = 0.1767766952966369f;  // 32^-0.5
  for (int mt = 0; mt < 4; mt++) {
    for (int r = 0; r < 4; r++) {
      int row = mt * 16 + quad * 4 + r;
      int ri = row / 7, rj = row - ri * 7;
      float vals[4];
      for (int nt = 0; nt < 4; nt++) {
        int col = nt * 16 + l16;
        float xv = S[mt][nt][r] * scale;
        if (col < NTOK && row < NTOK) {
          int ci = col / 7, cj = col - ci * 7;
          xv += table[((ri - ci + 6) * 13 + (rj - cj + 6)) * NHEAD + head];
        }
        if (col >= NTOK) xv = -1e30f;
        vals[nt] = xv;
      }
      float m = fmaxf(fmaxf(vals[0], vals[1]), fmaxf(vals[2], vals[3]));
      for (int off = 8; off >= 1; off >>= 1) m = fmaxf(m, __shfl_xor(m, off));
      float sum = 0.f;
      for (int nt = 0; nt < 4; nt++) {
        float e = __expf(vals[nt] - m);
        if (nt * 16 + l16 >= NTOK) e = 0.f;   // masked cols exactly 0 for PV
        vals[nt] = e; sum += e;
      }
      for (int off = 8; off >= 1; off >>= 1) sum += __shfl_xor(sum, off);
      float inv = 1.f / sum;
      for (int nt = 0; nt < 4; nt++)
        P[row * 64 + nt * 16 + l16] = (bf16_t)(vals[nt] * inv);
    }
  }
  __syncthreads();  // single wave: orders LDS writes vs reads

  // O = P V : A from P (16B contiguous), B from Vs (strided gather)
  f32x4 Oacc[4][2] = {};
  for (int kt = 0; kt < 2; kt++) {
    bf16x8 pf[4], vf[2];
    for (int mt = 0; mt < 4; mt++)
      pf[mt] = *(const bf16x8*)(P + (mt * 16 + l16) * 64 + kt * 32 + quad * 8);
    for (int nt = 0; nt < 2; nt++) {
      bf16x8 tmp;
      for (int j = 0; j < 8; j++)
        tmp[j] = Vs[(kt * 32 + quad * 8 + j) * HD + nt * 16 + l16];
      vf[nt] = tmp;
    }
    for (int mt = 0; mt < 4; mt++)
      for (int nt = 0; nt < 2; nt++)
        Oacc[mt][nt] = __builtin_amdgcn_mfma_f32_16x16x32_bf16(pf[mt], vf[nt], Oacc[mt][nt], 0, 0, 0);
  }

  // write O[win][n][head*32+d] (token-major layout = proj GEMM A)
  for (int mt = 0; mt < 4; mt++) {
    for (int r = 0; r < 4; r++) {
      int row = mt * 16 + quad * 4 + r;
      if (row < NTOK) {
        bf16_t* op = O + ((size_t)win * NTOK + row) * DD + head * HD;
        for (int nt = 0; nt < 2; nt++)
          op[nt * 16 + l16] = (bf16_t)Oacc[mt][nt][r];
      }
    }
  }
}

extern "C" void kernel_launch(void* const* d_in, const int* in_sizes, int n_in,
                              void* d_out, int out_size, void* d_ws, size_t ws_size,
                              hipStream_t stream) {
  const float* x      = (const float*)d_in[0];
  const float* ln_g   = (const float*)d_in[1];
  const float* ln_b   = (const float*)d_in[2];
  const float* qkv_w  = (const float*)d_in[3];
  const float* qkv_b  = (const float*)d_in[4];
  const float* proj_w = (const float*)d_in[5];
  const float* proj_b = (const float*)d_in[6];
  const float* table  = (const float*)d_in[7];
  float* out = (float*)d_out;

  const size_t SZ = (size_t)TOK * DD * 2;  // 57,802,752 B per [75264][384] bf16 buffer
  char* ws = (char*)d_ws;
  bf16_t* xw  = (bf16_t*)ws;               // reused as attention output O
  bf16_t* q   = (bf16_t*)(ws + SZ);
  bf16_t* k   = (bf16_t*)(ws + 2 * SZ);
  bf16_t* v   = (bf16_t*)(ws + 3 * SZ);
  bf16_t* qkv_wT  = (bf16_t*)(ws + 4 * SZ);            // [1152][384] bf16
  bf16_t* proj_wT = (bf16_t*)(ws + 4 * SZ + 884736);   // [384][384] bf16

  k_ln<<<TOK, 64, 0, stream>>>(x, ln_g, ln_b, xw);
  k_transpose<<<(DD / 32) * (DD3 / 32), 256, 0, stream>>>(qkv_w, qkv_wT, DD, DD3);
  k_transpose<<<(DD / 32) * (DD / 32), 256, 0, stream>>>(proj_w, proj_wT, DD, DD);
  k_gemm<0><<<dim3(9, 588), 256, 0, stream>>>(xw, qkv_wT, qkv_b, q, k, v, nullptr);
  k_attn<<<NWIN * NHEAD, 64, 0, stream>>>(q, k, v, table, xw);
  k_gemm<1><<<dim3(3, 588), 256, 0, stream>>>(xw, proj_wT, proj_b, nullptr, nullptr, nullptr, out);
}

// Round 2
// 465.467 us; speedup vs baseline: 1.3303x; 1.3303x over previous
//
#include <hip/hip_runtime.h>

typedef __bf16 bf16_t;
typedef __bf16 bf16x8 __attribute__((ext_vector_type(8)));
typedef __bf16 bf16x2 __attribute__((ext_vector_type(2)));
typedef float f32x4 __attribute__((ext_vector_type(4)));

#define TOK   75264   // 24 * 56 * 56 tokens
#define NWIN  1536    // 24 * 8 * 8 windows
#define DD    384
#define DD3   1152
#define NHEAD 12
#define HD    32
#define NTOK  49      // tokens per window
#define PSTR  72      // P LDS row stride (elems): 16B-aligned rows, banks spread
#define PWAVE 3528    // 49 * 72 elems per-wave P
#define PTAIL 1088    // covers reads up to row 63 from wave-3 base

// ---------------- K1: LayerNorm + window partition + bf16 cast ----------------
__global__ __launch_bounds__(64) void k_ln(const float* __restrict__ x,
                                           const float* __restrict__ g,
                                           const float* __restrict__ b,
                                           bf16_t* __restrict__ xw) {
  int row = blockIdx.x;                 // win*49 + n
  int win = row / NTOK, n = row - win * NTOK;
  int bt = win >> 6, wrem = win & 63;
  int n7 = n / 7;
  int hh = (wrem >> 3) * 7 + n7;
  int wc = (wrem & 7) * 7 + (n - n7 * 7);
  const float* xp = x + ((size_t)bt * 3136 + hh * 56 + wc) * DD;
  int lane = threadIdx.x;
  float2 v[3];
  float s = 0.f, s2 = 0.f;
  for (int i = 0; i < 3; i++) {
    float2 t = *(const float2*)(xp + 2 * lane + 128 * i);
    v[i] = t;
    s += t.x + t.y; s2 += t.x * t.x + t.y * t.y;
  }
  for (int off = 1; off < 64; off <<= 1) {
    s += __shfl_xor(s, off);
    s2 += __shfl_xor(s2, off);
  }
  float mu = s * (1.f / 384.f);
  float rs = rsqrtf(s2 * (1.f / 384.f) - mu * mu + 1e-5f);
  bf16_t* op = xw + (size_t)row * DD;
  for (int i = 0; i < 3; i++) {
    int d = 2 * lane + 128 * i;
    float2 gg = *(const float2*)(g + d);
    float2 bb = *(const float2*)(b + d);
    bf16x2 y;
    y[0] = (bf16_t)((v[i].x - mu) * rs * gg.x + bb.x);
    y[1] = (bf16_t)((v[i].y - mu) * rs * gg.y + bb.y);
    *(bf16x2*)(op + d) = y;
  }
}

// ---------------- K2: transpose + cast weights (R x C fp32 -> C x R bf16) ----------------
__global__ __launch_bounds__(256) void k_transpose(const float* __restrict__ src,
                                                   bf16_t* __restrict__ dst,
                                                   int R, int C) {
  __shared__ float t[32][33];
  int nbc = C / 32;
  int bc = blockIdx.x % nbc, br = blockIdx.x / nbc;
  int lx = threadIdx.x & 31, ly = threadIdx.x >> 5;   // 32 x 8
  for (int i = 0; i < 32; i += 8)
    t[ly + i][lx] = src[(size_t)(br * 32 + ly + i) * C + bc * 32 + lx];
  __syncthreads();
  for (int i = 0; i < 32; i += 8)
    dst[(size_t)(bc * 32 + ly + i) * R + br * 32 + lx] = (bf16_t)t[lx][ly + i];
}

// ---------------- K3/K5: 128x128 bf16 MFMA GEMM (m97 structure, B^T input) ----------------
// MODE 0: A=[token][384];  epilogue -> q/k/v [wh][49][32] bf16
// MODE 1: A=[wh][49][32] (attention O); epilogue -> un-window to fp32 output
template <int MODE>
__global__ __launch_bounds__(256) void k_gemm(
    const bf16_t* __restrict__ A,
    const bf16_t* __restrict__ BT,   // [N][384] row-major (transposed weight)
    const float* __restrict__ bias,  // [N]
    bf16_t* __restrict__ oq, bf16_t* __restrict__ ok, bf16_t* __restrict__ ov,
    float* __restrict__ out) {
  __shared__ bf16_t As[128 * 32];
  __shared__ bf16_t Bs[128 * 32];
  const int tid = threadIdx.x, wave = tid >> 6, lane = tid & 63;
  const int tn = blockIdx.x, tm = blockIdx.y;   // tn fastest: weight tile L2-resident
  const int K = 384;

  // staging: each wave covers 32 rows of its tile (2 issues of 64 lanes x 16B)
  const int arow0 = tm * 128 + wave * 32 + (lane >> 2);
  const bf16_t* ag0;
  const bf16_t* ag1;
  if constexpr (MODE == 1) {
    // permuted A layout [win][head][n][32]; BK=32 == HD, so k-step == next head
    int w0 = arow0 / NTOK, n0 = arow0 - w0 * NTOK;
    int r1 = arow0 + 16;
    int w1 = r1 / NTOK, n1 = r1 - w1 * NTOK;
    ag0 = A + ((size_t)w0 * NHEAD * NTOK + n0) * HD + (lane & 3) * 8;
    ag1 = A + ((size_t)w1 * NHEAD * NTOK + n1) * HD + (lane & 3) * 8;
  } else {
    ag0 = A + (size_t)arow0 * K + (lane & 3) * 8;
    ag1 = ag0 + 16 * K;
  }
  const int astep = (MODE == 1) ? (NTOK * HD) : 32;
  const bf16_t* bg = BT + (size_t)(tn * 128 + wave * 32 + (lane >> 2)) * K + (lane & 3) * 8;
  char* asl = (char*)&As[0] + wave * 2048;
  char* bsl = (char*)&Bs[0] + wave * 2048;

  const int wm = (wave & 1) * 64, wn = (wave >> 1) * 64;
  const int l16 = lane & 15, quad = lane >> 4;
  f32x4 acc[4][4] = {};

  for (int kk = 0; kk < K; kk += 32) {
    __syncthreads();  // previous compute done before LDS overwrite
    __builtin_amdgcn_global_load_lds((const __attribute__((address_space(1))) void*)(ag0),
                                     (__attribute__((address_space(3))) void*)(asl), 16, 0, 0);
    __builtin_amdgcn_global_load_lds((const __attribute__((address_space(1))) void*)(ag1),
                                     (__attribute__((address_space(3))) void*)(asl + 1024), 16, 0, 0);
    __builtin_amdgcn_global_load_lds((const __attribute__((address_space(1))) void*)(bg),
                                     (__attribute__((address_space(3))) void*)(bsl), 16, 0, 0);
    __builtin_amdgcn_global_load_lds((const __attribute__((address_space(1))) void*)(bg + 16 * K),
                                     (__attribute__((address_space(3))) void*)(bsl + 1024), 16, 0, 0);
    ag0 += astep; ag1 += astep; bg += 32;
    __syncthreads();  // drains vmcnt before barrier -> staging complete
    bf16x8 af[4], bf[4];
    for (int t = 0; t < 4; t++) {
      af[t] = *(const bf16x8*)&As[(wm + t * 16 + l16) * 32 + quad * 8];
      bf[t] = *(const bf16x8*)&Bs[(wn + t * 16 + l16) * 32 + quad * 8];
    }
    for (int mt = 0; mt < 4; mt++)
      for (int nt = 0; nt < 4; nt++)
        acc[mt][nt] = __builtin_amdgcn_mfma_f32_16x16x32_bf16(af[mt], bf[nt], acc[mt][nt], 0, 0, 0);
  }

  // epilogue: C/D layout col = lane&15, row = quad*4 + reg  [m89-verified]
  const int col0 = tn * 128 + wn + l16;
  const int row0 = tm * 128 + wm + quad * 4;
  if constexpr (MODE == 0) {
    int qi = tn / 3;  // 3 column-tiles (384 cols) per q/k/v
    bf16_t* dst = (qi == 0) ? oq : ((qi == 1) ? ok : ov);
    for (int mt = 0; mt < 4; mt++) {
      for (int r = 0; r < 4; r++) {
        int row = row0 + mt * 16 + r;
        int win = row / NTOK, n = row - win * NTOK;
        for (int nt = 0; nt < 4; nt++) {
          int col = col0 + nt * 16;
          float val = acc[mt][nt][r] + bias[col];
          int cidx = col - qi * 384;
          int head = cidx >> 5, d = cidx & 31;
          dst[(((size_t)(win * NHEAD + head) * NTOK + n) << 5) + d] = (bf16_t)val;
        }
      }
    }
  } else {
    for (int mt = 0; mt < 4; mt++) {
      for (int r = 0; r < 4; r++) {
        int row = row0 + mt * 16 + r;
        int win = row / NTOK, n = row - win * NTOK;
        int bt = win >> 6, wrem = win & 63;
        int n7 = n / 7;
        int hh = (wrem >> 3) * 7 + n7;
        int wc = (wrem & 7) * 7 + (n - n7 * 7);
        float* op = out + ((size_t)bt * 3136 + hh * 56 + wc) * DD;
        for (int nt = 0; nt < 4; nt++) {
          int col = col0 + nt * 16;
          op[col] = acc[mt][nt][r] + bias[col];
        }
      }
    }
  }
}

// ---------------- K4: windowed attention, 4 waves/block, one wave per (win,head) ----------------
__global__ __launch_bounds__(256) void k_attn(const bf16_t* __restrict__ q,
                                              const bf16_t* __restrict__ k,
                                              const bf16_t* __restrict__ v,
                                              const float* __restrict__ table,
                                              bf16_t* __restrict__ O) {
  __shared__ bf16_t Pb[4 * PWAVE + PTAIL];  // softmax probs, per-wave, row stride 72
  const int wave = threadIdx.x >> 6, lane = threadIdx.x & 63;
  const int wh = blockIdx.x * 4 + wave;     // win*12 + head
  const int head = wh % NHEAD;
  const int l16 = lane & 15, quad = lane >> 4;
  bf16_t* Pw = Pb + wave * PWAVE;
  const bf16_t* qp = q + (size_t)wh * NTOK * HD;
  const bf16_t* kp = k + (size_t)wh * NTOK * HD;
  const bf16_t* vp = v + (size_t)wh * NTOK * HD;

  // q/k fragments straight from global: A[m][kd], m=l16(+16*mt), kd=quad*8+j (16B contiguous)
  bf16x8 zz = {};
  bf16x8 qf[4], kf[4];
  for (int t = 0; t < 4; t++) {
    int m = t * 16 + l16;
    if (m < NTOK) {
      qf[t] = *(const bf16x8*)(qp + m * HD + quad * 8);
      kf[t] = *(const bf16x8*)(kp + m * HD + quad * 8);
    } else { qf[t] = zz; kf[t] = zz; }
  }

  // S = q k^T  (64x64 padded, hd=32 = one K step)
  f32x4 S[4][4] = {};
  for (int mt = 0; mt < 4; mt++)
    for (int nt = 0; nt < 4; nt++)
      S[mt][nt] = __builtin_amdgcn_mfma_f32_16x16x32_bf16(qf[mt], kf[nt], S[mt][nt], 0, 0, 0);

  // scale + rel-bias + masked softmax per row; row lives in one quad (16 lanes)
  const float scale = 0.1767766952966369f;  // 32^-0.5
  for (int mt = 0; mt < 4; mt++) {
    for (int r = 0; r < 4; r++) {
      int row = mt * 16 + quad * 4 + r;
      int ri = row / 7, rj = row - ri * 7;
      float vals[4];
      for (int nt = 0; nt < 4; nt++) {
        int col = nt * 16 + l16;
        float xv = S[mt][nt][r] * scale;
        if (col < NTOK && row < NTOK) {
          int ci = col / 7, cj = col - ci * 7;
          xv += table[((ri - ci + 6) * 13 + (rj - cj + 6)) * NHEAD + head];
        }
        if (col >= NTOK) xv = -1e30f;
        vals[nt] = xv;
      }
      float m = fmaxf(fmaxf(vals[0], vals[1]), fmaxf(vals[2], vals[3]));
      for (int off = 8; off >= 1; off >>= 1) m = fmaxf(m, __shfl_xor(m, off));
      float sum = 0.f;
      for (int nt = 0; nt < 4; nt++) {
        float e = __expf(vals[nt] - m);
        if (nt * 16 + l16 >= NTOK) e = 0.f;   // masked cols exactly 0 for PV
        vals[nt] = e; sum += e;
      }
      for (int off = 8; off >= 1; off >>= 1) sum += __shfl_xor(sum, off);
      float inv = 1.f / sum;
      if (row < NTOK)
        for (int nt = 0; nt < 4; nt++)
          Pw[row * PSTR + nt * 16 + l16] = (bf16_t)(vals[nt] * inv);
    }
  }
  __syncthreads();  // orders per-wave LDS writes vs reads (and keeps waves together)

  // O = P V : A-frag from P (16B contiguous, padded stride), B-frag gathered from global
  f32x4 Oacc[4][2] = {};
  for (int kt = 0; kt < 2; kt++) {
    bf16x8 pf[4], vf[2];
    for (int mt = 0; mt < 4; mt++)
      pf[mt] = *(const bf16x8*)(Pw + (mt * 16 + l16) * PSTR + kt * 32 + quad * 8);
    for (int nt = 0; nt < 2; nt++) {
      bf16x8 tmp;
      for (int j = 0; j < 8; j++) {
        int row = kt * 32 + quad * 8 + j;
        bf16_t val = (bf16_t)0.f;
        if (row < NTOK) val = vp[row * HD + nt * 16 + l16];  // 32B/quad, L2-merged
        tmp[j] = val;
      }
      vf[nt] = tmp;
    }
    for (int mt = 0; mt < 4; mt++)
      for (int nt = 0; nt < 2; nt++)
        Oacc[mt][nt] = __builtin_amdgcn_mfma_f32_16x16x32_bf16(pf[mt], vf[nt], Oacc[mt][nt], 0, 0, 0);
  }

  // write O[wh][n][d]: each 64B row owned entirely by this wave -> clean lines
  for (int mt = 0; mt < 4; mt++) {
    for (int r = 0; r < 4; r++) {
      int row = mt * 16 + quad * 4 + r;
      if (row < NTOK) {
        bf16_t* op = O + ((size_t)wh * NTOK + row) * HD;
        for (int nt = 0; nt < 2; nt++)
          op[nt * 16 + l16] = (bf16_t)Oacc[mt][nt][r];
      }
    }
  }
}

extern "C" void kernel_launch(void* const* d_in, const int* in_sizes, int n_in,
                              void* d_out, int out_size, void* d_ws, size_t ws_size,
                              hipStream_t stream) {
  const float* x      = (const float*)d_in[0];
  const float* ln_g   = (const float*)d_in[1];
  const float* ln_b   = (const float*)d_in[2];
  const float* qkv_w  = (const float*)d_in[3];
  const float* qkv_b  = (const float*)d_in[4];
  const float* proj_w = (const float*)d_in[5];
  const float* proj_b = (const float*)d_in[6];
  const float* table  = (const float*)d_in[7];
  float* out = (float*)d_out;

  const size_t SZ = (size_t)TOK * DD * 2;  // 57,802,752 B per [75264][384] bf16 buffer
  char* ws = (char*)d_ws;
  bf16_t* xw  = (bf16_t*)ws;               // LN out; reused as attention O ([wh][49][32])
  bf16_t* q   = (bf16_t*)(ws + SZ);
  bf16_t* k   = (bf16_t*)(ws + 2 * SZ);
  bf16_t* v   = (bf16_t*)(ws + 3 * SZ);
  bf16_t* qkv_wT  = (bf16_t*)(ws + 4 * SZ);            // [1152][384] bf16
  bf16_t* proj_wT = (bf16_t*)(ws + 4 * SZ + 884736);   // [384][384] bf16

  k_ln<<<TOK, 64, 0, stream>>>(x, ln_g, ln_b, xw);
  k_transpose<<<(DD / 32) * (DD3 / 32), 256, 0, stream>>>(qkv_w, qkv_wT, DD, DD3);
  k_transpose<<<(DD / 32) * (DD / 32), 256, 0, stream>>>(proj_w, proj_wT, DD, DD);
  k_gemm<0><<<dim3(9, 588), 256, 0, stream>>>(xw, qkv_wT, qkv_b, q, k, v, nullptr);
  k_attn<<<NWIN * NHEAD / 4, 256, 0, stream>>>(q, k, v, table, xw);
  k_gemm<1><<<dim3(3, 588), 256, 0, stream>>>(xw, proj_wT, proj_b, nullptr, nullptr, nullptr, out);
}

// Round 3
// 440.690 us; speedup vs baseline: 1.4051x; 1.0562x over previous
//
#include <hip/hip_runtime.h>

typedef __bf16 bf16_t;
typedef __bf16 bf16x8 __attribute__((ext_vector_type(8)));
typedef __bf16 bf16x2 __attribute__((ext_vector_type(2)));
typedef float f32x4 __attribute__((ext_vector_type(4)));

#define TOK   75264   // 24 * 56 * 56 tokens
#define NWIN  1536    // 24 * 8 * 8 windows
#define DD    384
#define DD3   1152
#define NHEAD 12
#define HD    32
#define NTOK  49      // tokens per window
#define NTM   588     // row tiles (75264 / 128)
#define PSTR  72      // P LDS row stride (elems): 16B-aligned rows, banks spread
#define PWAVE 3528    // 49 * 72 elems per-wave P
#define PTAIL 1088    // covers reads up to row 63 from wave-3 base

// ---------------- K1: LayerNorm + window partition + bf16 cast ----------------
// 4 waves/block, one window-ordered token row per wave
__global__ __launch_bounds__(256) void k_ln(const float* __restrict__ x,
                                            const float* __restrict__ g,
                                            const float* __restrict__ b,
                                            bf16_t* __restrict__ xw) {
  int row = blockIdx.x * 4 + (threadIdx.x >> 6);   // win*49 + n
  int win = row / NTOK, n = row - win * NTOK;
  int bt = win >> 6, wrem = win & 63;
  int n7 = n / 7;
  int hh = (wrem >> 3) * 7 + n7;
  int wc = (wrem & 7) * 7 + (n - n7 * 7);
  const float* xp = x + ((size_t)bt * 3136 + hh * 56 + wc) * DD;
  int lane = threadIdx.x & 63;
  float2 v[3];
  float s = 0.f, s2 = 0.f;
  for (int i = 0; i < 3; i++) {
    float2 t = *(const float2*)(xp + 2 * lane + 128 * i);
    v[i] = t;
    s += t.x + t.y; s2 += t.x * t.x + t.y * t.y;
  }
  for (int off = 1; off < 64; off <<= 1) {
    s += __shfl_xor(s, off);
    s2 += __shfl_xor(s2, off);
  }
  float mu = s * (1.f / 384.f);
  float rs = rsqrtf(s2 * (1.f / 384.f) - mu * mu + 1e-5f);
  bf16_t* op = xw + (size_t)row * DD;
  for (int i = 0; i < 3; i++) {
    int d = 2 * lane + 128 * i;
    float2 gg = *(const float2*)(g + d);
    float2 bb = *(const float2*)(b + d);
    bf16x2 y;
    y[0] = (bf16_t)((v[i].x - mu) * rs * gg.x + bb.x);
    y[1] = (bf16_t)((v[i].y - mu) * rs * gg.y + bb.y);
    *(bf16x2*)(op + d) = y;
  }
}

// ---------------- K2: transpose + cast weights (R x C fp32 -> C x R bf16) ----------------
__global__ __launch_bounds__(256) void k_transpose(const float* __restrict__ src,
                                                   bf16_t* __restrict__ dst,
                                                   int R, int C) {
  __shared__ float t[32][33];
  int nbc = C / 32;
  int bc = blockIdx.x % nbc, br = blockIdx.x / nbc;
  int lx = threadIdx.x & 31, ly = threadIdx.x >> 5;   // 32 x 8
  for (int i = 0; i < 32; i += 8)
    t[ly + i][lx] = src[(size_t)(br * 32 + ly + i) * C + bc * 32 + lx];
  __syncthreads();
  for (int i = 0; i < 32; i += 8)
    dst[(size_t)(bc * 32 + ly + i) * R + br * 32 + lx] = (bf16_t)t[lx][ly + i];
}

// ---------------- K3/K5: 128x128 bf16 MFMA GEMM (m97 structure, B^T input) ----------------
// 1-D grid, XCD-affinity swizzle: all NTN col-tiles of one row-tile land on one XCD,
// so the 98KB A-tile is fetched into exactly one L2. (Dispatch->XCD = bid % 8.)
// MODE 0: A=[token][384];  epilogue -> q/k/v [wh][49][32] bf16   (NTN=9)
// MODE 1: A=[wh][49][32] (attention O); epilogue -> fp32 unwindowed out (NTN=3)
template <int MODE>
__global__ __launch_bounds__(256) void k_gemm(
    const bf16_t* __restrict__ A,
    const bf16_t* __restrict__ BT,   // [N][384] row-major (transposed weight)
    const float* __restrict__ bias,  // [N]
    bf16_t* __restrict__ oq, bf16_t* __restrict__ ok, bf16_t* __restrict__ ov,
    float* __restrict__ out) {
  __shared__ bf16_t As[128 * 32];
  __shared__ bf16_t Bs[128 * 32];
  const int tid = threadIdx.x, wave = tid >> 6, lane = tid & 63;
  constexpr int NTN = (MODE == 0) ? 9 : 3;
  constexpr int GRP = 8 * NTN;          // one swizzle group: 8 row-tiles x NTN col-tiles
  constexpr int NFULL = (NTM / 8) * GRP;
  int tm, tn;
  {
    int bid = blockIdx.x;
    if (bid < NFULL) {
      int g = bid / GRP, r = bid % GRP;
      tn = r >> 3;
      tm = g * 8 + (r & 7);
    } else {                            // tail: last NTM%8 = 4 row-tiles
      int r = bid - NFULL;
      tn = r >> 2;
      tm = (NTM & ~7) + (r & 3);
    }
  }
  const int K = 384;

  // staging: each wave covers 32 rows of its tile (2 issues of 64 lanes x 16B)
  const int arow0 = tm * 128 + wave * 32 + (lane >> 2);
  const bf16_t* ag0;
  const bf16_t* ag1;
  if constexpr (MODE == 1) {
    // permuted A layout [win][head][n][32]; BK=32 == HD, so k-step == next head
    int w0 = arow0 / NTOK, n0 = arow0 - w0 * NTOK;
    int r1 = arow0 + 16;
    int w1 = r1 / NTOK, n1 = r1 - w1 * NTOK;
    ag0 = A + ((size_t)w0 * NHEAD * NTOK + n0) * HD + (lane & 3) * 8;
    ag1 = A + ((size_t)w1 * NHEAD * NTOK + n1) * HD + (lane & 3) * 8;
  } else {
    ag0 = A + (size_t)arow0 * K + (lane & 3) * 8;
    ag1 = ag0 + 16 * K;
  }
  const int astep = (MODE == 1) ? (NTOK * HD) : 32;
  const bf16_t* bg = BT + (size_t)(tn * 128 + wave * 32 + (lane >> 2)) * K + (lane & 3) * 8;
  char* asl = (char*)&As[0] + wave * 2048;
  char* bsl = (char*)&Bs[0] + wave * 2048;

  const int wm = (wave & 1) * 64, wn = (wave >> 1) * 64;
  const int l16 = lane & 15, quad = lane >> 4;
  f32x4 acc[4][4] = {};

  for (int kk = 0; kk < K; kk += 32) {
    __syncthreads();  // previous compute done before LDS overwrite
    __builtin_amdgcn_global_load_lds((const __attribute__((address_space(1))) void*)(ag0),
                                     (__attribute__((address_space(3))) void*)(asl), 16, 0, 0);
    __builtin_amdgcn_global_load_lds((const __attribute__((address_space(1))) void*)(ag1),
                                     (__attribute__((address_space(3))) void*)(asl + 1024), 16, 0, 0);
    __builtin_amdgcn_global_load_lds((const __attribute__((address_space(1))) void*)(bg),
                                     (__attribute__((address_space(3))) void*)(bsl), 16, 0, 0);
    __builtin_amdgcn_global_load_lds((const __attribute__((address_space(1))) void*)(bg + 16 * K),
                                     (__attribute__((address_space(3))) void*)(bsl + 1024), 16, 0, 0);
    ag0 += astep; ag1 += astep; bg += 32;
    __syncthreads();  // drains vmcnt before barrier -> staging complete
    bf16x8 af[4], bf[4];
    for (int t = 0; t < 4; t++) {
      af[t] = *(const bf16x8*)&As[(wm + t * 16 + l16) * 32 + quad * 8];
      bf[t] = *(const bf16x8*)&Bs[(wn + t * 16 + l16) * 32 + quad * 8];
    }
    for (int mt = 0; mt < 4; mt++)
      for (int nt = 0; nt < 4; nt++)
        acc[mt][nt] = __builtin_amdgcn_mfma_f32_16x16x32_bf16(af[mt], bf[nt], acc[mt][nt], 0, 0, 0);
  }

  // epilogue: C/D layout col = lane&15, row = quad*4 + reg  [m89-verified]
  const int col0 = tn * 128 + wn + l16;
  const int row0 = tm * 128 + wm + quad * 4;
  if constexpr (MODE == 0) {
    int qi = tn / 3;  // 3 column-tiles (384 cols) per q/k/v
    bf16_t* dst = (qi == 0) ? oq : ((qi == 1) ? ok : ov);
    for (int mt = 0; mt < 4; mt++) {
      for (int r = 0; r < 4; r++) {
        int row = row0 + mt * 16 + r;
        int win = row / NTOK, n = row - win * NTOK;
        for (int nt = 0; nt < 4; nt++) {
          int col = col0 + nt * 16;
          float val = acc[mt][nt][r] + bias[col];
          int cidx = col - qi * 384;
          int head = cidx >> 5, d = cidx & 31;
          dst[(((size_t)(win * NHEAD + head) * NTOK + n) << 5) + d] = (bf16_t)val;
        }
      }
    }
  } else {
    for (int mt = 0; mt < 4; mt++) {
      for (int r = 0; r < 4; r++) {
        int row = row0 + mt * 16 + r;
        int win = row / NTOK, n = row - win * NTOK;
        int bt = win >> 6, wrem = win & 63;
        int n7 = n / 7;
        int hh = (wrem >> 3) * 7 + n7;
        int wc = (wrem & 7) * 7 + (n - n7 * 7);
        float* op = out + ((size_t)bt * 3136 + hh * 56 + wc) * DD;
        for (int nt = 0; nt < 4; nt++) {
          int col = col0 + nt * 16;
          op[col] = acc[mt][nt][r] + bias[col];
        }
      }
    }
  }
}

// ---------------- K4: windowed attention, 4 waves/block, one wave per (win,head) ----------------
__global__ __launch_bounds__(256) void k_attn(const bf16_t* __restrict__ q,
                                              const bf16_t* __restrict__ k,
                                              const bf16_t* __restrict__ v,
                                              const float* __restrict__ table,
                                              bf16_t* __restrict__ O) {
  __shared__ bf16_t Pb[4 * PWAVE + PTAIL];  // softmax probs, per-wave, row stride 72
  const int wave = threadIdx.x >> 6, lane = threadIdx.x & 63;
  const int wh = blockIdx.x * 4 + wave;     // win*12 + head
  const int head = wh % NHEAD;
  const int l16 = lane & 15, quad = lane >> 4;
  bf16_t* Pw = Pb + wave * PWAVE;
  const bf16_t* qp = q + (size_t)wh * NTOK * HD;
  const bf16_t* kp = k + (size_t)wh * NTOK * HD;
  const bf16_t* vp = v + (size_t)wh * NTOK * HD;

  // q/k fragments straight from global: A[m][kd], m=l16(+16*mt), kd=quad*8+j (16B contiguous)
  bf16x8 zz = {};
  bf16x8 qf[4], kf[4];
  for (int t = 0; t < 4; t++) {
    int m = t * 16 + l16;
    if (m < NTOK) {
      qf[t] = *(const bf16x8*)(qp + m * HD + quad * 8);
      kf[t] = *(const bf16x8*)(kp + m * HD + quad * 8);
    } else { qf[t] = zz; kf[t] = zz; }
  }

  // S = q k^T  (64x64 padded, hd=32 = one K step)
  f32x4 S[4][4] = {};
  for (int mt = 0; mt < 4; mt++)
    for (int nt = 0; nt < 4; nt++)
      S[mt][nt] = __builtin_amdgcn_mfma_f32_16x16x32_bf16(qf[mt], kf[nt], S[mt][nt], 0, 0, 0);

  // scale + rel-bias + masked softmax per row; row lives in one quad (16 lanes)
  const float scale = 0.1767766952966369f;  // 32^-0.5
  for (int mt = 0; mt < 4; mt++) {
    for (int r = 0; r < 4; r++) {
      int row = mt * 16 + quad * 4 + r;
      int ri = row / 7, rj = row - ri * 7;
      float vals[4];
      for (int nt = 0; nt < 4; nt++) {
        int col = nt * 16 + l16;
        float xv = S[mt][nt][r] * scale;
        if (col < NTOK && row < NTOK) {
          int ci = col / 7, cj = col - ci * 7;
          xv += table[((ri - ci + 6) * 13 + (rj - cj + 6)) * NHEAD + head];
        }
        if (col >= NTOK) xv = -1e30f;
        vals[nt] = xv;
      }
      float m = fmaxf(fmaxf(vals[0], vals[1]), fmaxf(vals[2], vals[3]));
      for (int off = 8; off >= 1; off >>= 1) m = fmaxf(m, __shfl_xor(m, off));
      float sum = 0.f;
      for (int nt = 0; nt < 4; nt++) {
        float e = __expf(vals[nt] - m);
        if (nt * 16 + l16 >= NTOK) e = 0.f;   // masked cols exactly 0 for PV
        vals[nt] = e; sum += e;
      }
      for (int off = 8; off >= 1; off >>= 1) sum += __shfl_xor(sum, off);
      float inv = 1.f / sum;
      if (row < NTOK)
        for (int nt = 0; nt < 4; nt++)
          Pw[row * PSTR + nt * 16 + l16] = (bf16_t)(vals[nt] * inv);
    }
  }
  __syncthreads();  // orders per-wave LDS writes vs reads (and keeps waves together)

  // O = P V : A-frag from P (16B contiguous, padded stride), B-frag gathered from global
  f32x4 Oacc[4][2] = {};
  for (int kt = 0; kt < 2; kt++) {
    bf16x8 pf[4], vf[2];
    for (int mt = 0; mt < 4; mt++)
      pf[mt] = *(const bf16x8*)(Pw + (mt * 16 + l16) * PSTR + kt * 32 + quad * 8);
    for (int nt = 0; nt < 2; nt++) {
      bf16x8 tmp;
      for (int j = 0; j < 8; j++) {
        int row = kt * 32 + quad * 8 + j;
        bf16_t val = (bf16_t)0.f;
        if (row < NTOK) val = vp[row * HD + nt * 16 + l16];  // 32B/quad, L2-merged
        tmp[j] = val;
      }
      vf[nt] = tmp;
    }
    for (int mt = 0; mt < 4; mt++)
      for (int nt = 0; nt < 2; nt++)
        Oacc[mt][nt] = __builtin_amdgcn_mfma_f32_16x16x32_bf16(pf[mt], vf[nt], Oacc[mt][nt], 0, 0, 0);
  }

  // write O[wh][n][d]: each 64B row owned entirely by this wave -> clean lines
  for (int mt = 0; mt < 4; mt++) {
    for (int r = 0; r < 4; r++) {
      int row = mt * 16 + quad * 4 + r;
      if (row < NTOK) {
        bf16_t* op = O + ((size_t)wh * NTOK + row) * HD;
        for (int nt = 0; nt < 2; nt++)
          op[nt * 16 + l16] = (bf16_t)Oacc[mt][nt][r];
      }
    }
  }
}

extern "C" void kernel_launch(void* const* d_in, const int* in_sizes, int n_in,
                              void* d_out, int out_size, void* d_ws, size_t ws_size,
                              hipStream_t stream) {
  const float* x      = (const float*)d_in[0];
  const float* ln_g   = (const float*)d_in[1];
  const float* ln_b   = (const float*)d_in[2];
  const float* qkv_w  = (const float*)d_in[3];
  const float* qkv_b  = (const float*)d_in[4];
  const float* proj_w = (const float*)d_in[5];
  const float* proj_b = (const float*)d_in[6];
  const float* table  = (const float*)d_in[7];
  float* out = (float*)d_out;

  const size_t SZ = (size_t)TOK * DD * 2;  // 57,802,752 B per [75264][384] bf16 buffer
  char* ws = (char*)d_ws;
  bf16_t* xw  = (bf16_t*)ws;               // LN out; reused as attention O ([wh][49][32])
  bf16_t* q   = (bf16_t*)(ws + SZ);
  bf16_t* k   = (bf16_t*)(ws + 2 * SZ);
  bf16_t* v   = (bf16_t*)(ws + 3 * SZ);
  bf16_t* qkv_wT  = (bf16_t*)(ws + 4 * SZ);            // [1152][384] bf16
  bf16_t* proj_wT = (bf16_t*)(ws + 4 * SZ + 884736);   // [384][384] bf16

  k_ln<<<TOK / 4, 256, 0, stream>>>(x, ln_g, ln_b, xw);
  k_transpose<<<(DD / 32) * (DD3 / 32), 256, 0, stream>>>(qkv_w, qkv_wT, DD, DD3);
  k_transpose<<<(DD / 32) * (DD / 32), 256, 0, stream>>>(proj_w, proj_wT, DD, DD);
  k_gemm<0><<<NTM * 9, 256, 0, stream>>>(xw, qkv_wT, qkv_b, q, k, v, nullptr);
  k_attn<<<NWIN * NHEAD / 4, 256, 0, stream>>>(q, k, v, table, xw);
  k_gemm<1><<<NTM * 3, 256, 0, stream>>>(xw, proj_wT, proj_b, nullptr, nullptr, nullptr, out);
}